// Round 2
// baseline (1630.229 us; speedup 1.0000x reference)
//
#include <hip/hip_runtime.h>

#define BB 512
#define TT 512
#define EE 64
#define HH 64
#define KK 9
#define VP1 30001   // V+1 rows in emb

typedef __attribute__((ext_vector_type(8))) short short8;
typedef __attribute__((ext_vector_type(4))) float float4v;

__device__ __forceinline__ float sigm(float x) { return 1.0f / (1.0f + __expf(-x)); }
__device__ __forceinline__ float tanh_(float x) { return 1.0f - 2.0f / (__expf(2.0f * x) + 1.0f); }

__device__ __forceinline__ unsigned short f2bf(float f) {
    unsigned int u = __float_as_uint(f);
    unsigned int r = u + 0x7fffu + ((u >> 16) & 1u);
    return (unsigned short)(r >> 16);
}
__device__ __forceinline__ float bflo2f(unsigned int d) { return __uint_as_float(d << 16); }
__device__ __forceinline__ float bfhi2f(unsigned int d) { return __uint_as_float(d & 0xffff0000u); }

// ---------------------------------------------------------------------------
// embW[v, dir, u, g] = sum_k emb[v,k] * W_dir[k, g*64+u] + b_dir[g*64+u]  (bf16)
// Swizzled so the 4 gate values of one unit are contiguous (8 B = one uint2).
// ---------------------------------------------------------------------------
__global__ __launch_bounds__(512)
void embw_kernel(const float* __restrict__ emb,
                 const float* __restrict__ Wf, const float* __restrict__ bfv,
                 const float* __restrict__ Wb, const float* __restrict__ bbv,
                 unsigned short* __restrict__ embw)
{
    const int v0 = blockIdx.x * 8;
    const int tid = threadIdx.x;
    __shared__ float ebuf[8][64];
    {
        int r = tid >> 6, k = tid & 63;
        int v = v0 + r;
        ebuf[r][k] = (v < VP1) ? emb[v * 64 + k] : 0.f;
    }
    __syncthreads();
    const int dir = tid >> 8, rest = tid & 255;
    const int u = rest >> 2, g = rest & 3;
    const int col = g * 64 + u;
    const float* Wp = dir ? Wb : Wf;
    const float bias = (dir ? bbv : bfv)[col];
    float acc[8];
#pragma unroll
    for (int r = 0; r < 8; ++r) acc[r] = bias;
#pragma unroll
    for (int k = 0; k < 64; ++k) {
        float wv = Wp[k * 256 + col];
#pragma unroll
        for (int r = 0; r < 8; ++r) acc[r] += ebuf[r][k] * wv;
    }
#pragma unroll
    for (int r = 0; r < 8; ++r) {
        int v = v0 + r;
        if (v < VP1) embw[((size_t)v * 2 + dir) * 256 + rest] = f2bf(acc[r]);
    }
}

// ---------------------------------------------------------------------------
// Recurrence: grid 64 = 2 dirs x 32 row-slices (16 rows). 4 waves/block, wave w
// owns units u = w*16 + (lane&15). U held as MFMA B-frags (32 VGPR bf16).
// Per step: h (16x64 bf16) via LDS -> A-frags; 8 MFMAs z=zx+h@U; gates in-lane;
// wave0: 2 MFMAs h@Wd -> potentials for previous step.
// ---------------------------------------------------------------------------
__global__ __launch_bounds__(256, 1)
void rec_kernel(const int* __restrict__ tokens,
                const unsigned short* __restrict__ embw,
                const float* __restrict__ Uf, const float* __restrict__ Ub,
                const float* __restrict__ Wd,
                float* __restrict__ potf, float* __restrict__ potb)
{
    const int blk = blockIdx.x;
    const int dir = blk >> 5;
    const int row0 = (blk & 31) * 16;
    const int tid = threadIdx.x;
    const int lane = tid & 63;
    const int w = tid >> 6;
    const int l16 = lane & 15, quad = lane >> 4;
    const int u = w * 16 + l16;

    const float* Up = dir ? Ub : Uf;
    float* pot = dir ? potb : potf;
    const uint2* embw2 = (const uint2*)embw;

    __shared__ __align__(16) unsigned short hl[2][16][72];

    // U B-fragments: bU[g][q][j] = U[k=q*32+quad*8+j][g*64+u]
    short8 bU[4][2];
#pragma unroll
    for (int g = 0; g < 4; ++g)
#pragma unroll
        for (int q = 0; q < 2; ++q) {
            short8 v;
#pragma unroll
            for (int j = 0; j < 8; ++j) {
                int k = q * 32 + quad * 8 + j;
                v[j] = (short)f2bf(Up[k * 256 + g * 64 + u]);
            }
            bU[g][q] = v;
        }
    // Wd B-fragments (cols 0..8 live, rest zero)
    short8 bW[2];
#pragma unroll
    for (int q = 0; q < 2; ++q) {
        short8 v;
#pragma unroll
        for (int j = 0; j < 8; ++j) {
            int k = q * 32 + quad * 8 + j;
            v[j] = (l16 < KK) ? (short)f2bf(Wd[(dir * 64 + k) * KK + l16]) : (short)0;
        }
        bW[q] = v;
    }

    int rowg[4];
#pragma unroll
    for (int r = 0; r < 4; ++r) rowg[r] = row0 + quad * 4 + r;

    // prologue: tokens for step0 & step1, zx gather for step0
    int tok_cur[4], tok_nxt[4], tok_n2[4];
    uint2 zx_cur[4], zx_nxt[4];
#pragma unroll
    for (int r = 0; r < 4; ++r) {
        int t0 = dir ? (TT - 1) : 0;
        tok_cur[r] = tokens[rowg[r] * TT + t0];
    }
#pragma unroll
    for (int r = 0; r < 4; ++r)
        zx_cur[r] = embw2[(size_t)(tok_cur[r] * 2 + dir) * 64 + u];
#pragma unroll
    for (int r = 0; r < 4; ++r) {
        int t1 = dir ? (TT - 2) : 1;
        tok_nxt[r] = tokens[rowg[r] * TT + t1];
    }

    float c_st[4] = {0.f, 0.f, 0.f, 0.f};
    float h_st[4] = {0.f, 0.f, 0.f, 0.f};

    for (int s = 0; s < TT; ++s) {
        // publish h_{s} (input state of step s)
#pragma unroll
        for (int r = 0; r < 4; ++r)
            hl[s & 1][quad * 4 + r][u] = f2bf(h_st[r]);
        __syncthreads();

        // prefetch next-step zx and tokens two ahead
        if (s + 1 < TT) {
#pragma unroll
            for (int r = 0; r < 4; ++r)
                zx_nxt[r] = embw2[(size_t)(tok_nxt[r] * 2 + dir) * 64 + u];
            if (s + 2 < TT) {
                int t2 = dir ? (TT - 3 - s) : (s + 2);
#pragma unroll
                for (int r = 0; r < 4; ++r)
                    tok_n2[r] = tokens[rowg[r] * TT + t2];
            }
        }

        // A-fragments of h from LDS
        const unsigned short* hrow = &hl[s & 1][l16][0];
        short8 a0 = *(const short8*)(hrow + quad * 8);
        short8 a1 = *(const short8*)(hrow + 32 + quad * 8);

        // z = zx + h @ U
        float4v accg[4];
#pragma unroll
        for (int r = 0; r < 4; ++r) {
            accg[0][r] = bflo2f(zx_cur[r].x);
            accg[1][r] = bfhi2f(zx_cur[r].x);
            accg[2][r] = bflo2f(zx_cur[r].y);
            accg[3][r] = bfhi2f(zx_cur[r].y);
        }
#pragma unroll
        for (int g = 0; g < 4; ++g) {
            accg[g] = __builtin_amdgcn_mfma_f32_16x16x32_bf16(a0, bU[g][0], accg[g], 0, 0, 0);
            accg[g] = __builtin_amdgcn_mfma_f32_16x16x32_bf16(a1, bU[g][1], accg[g], 0, 0, 0);
        }

        // wave0: potentials for previous step (h_lds holds h after step s-1)
        if (w == 0 && s > 0) {
            float4v accP = {0.f, 0.f, 0.f, 0.f};
            accP = __builtin_amdgcn_mfma_f32_16x16x32_bf16(a0, bW[0], accP, 0, 0, 0);
            accP = __builtin_amdgcn_mfma_f32_16x16x32_bf16(a1, bW[1], accP, 0, 0, 0);
            int tprev = dir ? (TT - s) : (s - 1);
            if (l16 < KK) {
#pragma unroll
                for (int r = 0; r < 4; ++r)
                    pot[((size_t)(row0 + quad * 4 + r) * TT + tprev) * KK + l16] = accP[r];
            }
        }

        // gates (lane owns unit u for 4 rows)
#pragma unroll
        for (int r = 0; r < 4; ++r) {
            float zi = accg[0][r], zf = accg[1][r], zg = accg[2][r], zo = accg[3][r];
            float cn = sigm(zf) * c_st[r] + sigm(zi) * tanh_(zg);
            float hn = sigm(zo) * tanh_(cn);
            bool m = (tok_cur[r] != 0);
            h_st[r] = m ? hn : h_st[r];
            c_st[r] = m ? cn : c_st[r];
        }

        // rotate pipeline regs
#pragma unroll
        for (int r = 0; r < 4; ++r) {
            tok_cur[r] = tok_nxt[r];
            tok_nxt[r] = tok_n2[r];
            zx_cur[r] = zx_nxt[r];
        }
    }

    // epilogue: potential for the final step
#pragma unroll
    for (int r = 0; r < 4; ++r)
        hl[0][quad * 4 + r][u] = f2bf(h_st[r]);
    __syncthreads();
    if (w == 0) {
        const unsigned short* hrow = &hl[0][l16][0];
        short8 a0 = *(const short8*)(hrow + quad * 8);
        short8 a1 = *(const short8*)(hrow + 32 + quad * 8);
        float4v accP = {0.f, 0.f, 0.f, 0.f};
        accP = __builtin_amdgcn_mfma_f32_16x16x32_bf16(a0, bW[0], accP, 0, 0, 0);
        accP = __builtin_amdgcn_mfma_f32_16x16x32_bf16(a1, bW[1], accP, 0, 0, 0);
        int tlast = dir ? 0 : (TT - 1);
        if (l16 < KK) {
#pragma unroll
            for (int r = 0; r < 4; ++r)
                pot[((size_t)(row0 + quad * 4 + r) * TT + tlast) * KK + l16] = accP[r];
        }
    }
}

// ---------------------------------------------------------------------------
// Fused combine + Viterbi. One wave per batch row. Potentials staged through
// LDS with coalesced loads; segmented parallel backtrace (64 segments of 8).
// ---------------------------------------------------------------------------
__global__ __launch_bounds__(64)
void viterbi_kernel(const int* __restrict__ tokens,
                    const float* __restrict__ potf, const float* __restrict__ potb,
                    const float* __restrict__ bd, const float* __restrict__ trans,
                    float* __restrict__ dec_out, float* __restrict__ pot_out,
                    float* __restrict__ seq_out)
{
    const int row = blockIdx.x;
    const int lane = threadIdx.x;

    __shared__ float pl[TT * KK];                 // 18432 B (potf+potb, no bd)
    __shared__ unsigned char bpl[(TT - 1) * KK];  // 4599 B
    __shared__ unsigned char maskl[TT];
    __shared__ unsigned char segmap[64][KK];
    __shared__ unsigned char bseq[65];
    __shared__ float decl_[TT];

    // masks + seq_len
    int cnt = 0;
#pragma unroll
    for (int ch = 0; ch < TT / 64; ++ch) {
        int tk = tokens[row * TT + ch * 64 + lane];
        int m = (tk != 0) ? 1 : 0;
        maskl[ch * 64 + lane] = (unsigned char)m;
        cnt += m;
    }
    for (int off = 32; off > 0; off >>= 1) cnt += __shfl_down(cnt, off);
    if (lane == 0) seq_out[row] = (float)cnt;

    // stage potentials (coalesced) + write pot_out with bias
    const size_t base = (size_t)row * (TT * KK);
    for (int i = 0; i < (TT * KK) / 64; ++i) {
        int li = i * 64 + lane;
        float s = potf[base + li] + potb[base + li];
        pl[li] = s;
        pot_out[base + li] = s + bd[li % KK];
    }
    __syncthreads();

    float bdv = (lane < KK) ? bd[lane] : 0.f;
    float treg[KK];
#pragma unroll
    for (int i = 0; i < KK; ++i) treg[i] = (lane < KK) ? trans[i * KK + lane] : 0.f;

    float alpha = (lane < KK) ? (pl[lane] + bdv) : -1e30f;
    for (int t = 1; t < TT; ++t) {
        float p = (lane < KK) ? (pl[t * KK + lane] + bdv) : 0.f;
        float best = -1e30f; int arg = 0;
#pragma unroll
        for (int i = 0; i < KK; ++i) {
            float sc = __shfl(alpha, i) + treg[i];
            if (sc > best) { best = sc; arg = i; }  // strict > = first-max (np.argmax)
        }
        bool m = maskl[t] != 0;
        alpha = m ? (best + p) : alpha;
        int bpv = m ? arg : lane;
        if (lane < KK) bpl[(t - 1) * KK + lane] = (unsigned char)bpv;
    }
    float bestA = -1e30f; int last = 0;
#pragma unroll
    for (int i = 0; i < KK; ++i) {
        float ai = __shfl(alpha, i);
        if (ai > bestA) { bestA = ai; last = i; }
    }
    __syncthreads();

    // segmented backtrace: lane l composes bp maps over t in [8l, 8l+8)
    {
        int l = lane;
#pragma unroll
        for (int x = 0; x < KK; ++x) {
            int y = x;
#pragma unroll
            for (int d = 7; d >= 0; --d) {
                int t = 8 * l + d;
                if (t < TT - 1) y = bpl[t * KK + y];
            }
            segmap[l][x] = (unsigned char)y;
        }
    }
    __syncthreads();
    if (lane == 0) {
        int cur = last;
        bseq[64] = (unsigned char)last;
        for (int l = 63; l >= 0; --l) {
            cur = segmap[l][cur];
            bseq[l] = (unsigned char)cur;
        }
    }
    __syncthreads();
    {
        int l = lane;
        int cur = bseq[l + 1];
#pragma unroll
        for (int d = 7; d >= 0; --d) {
            int t = 8 * l + d;
            if (t < TT - 1) cur = bpl[t * KK + cur];
            decl_[t] = (maskl[t] != 0) ? (float)cur : 0.f;
        }
    }
    __syncthreads();
#pragma unroll
    for (int ch = 0; ch < TT / 64; ++ch)
        dec_out[(size_t)row * TT + ch * 64 + lane] = decl_[ch * 64 + lane];
}

extern "C" void kernel_launch(void* const* d_in, const int* in_sizes, int n_in,
                              void* d_out, int out_size, void* d_ws, size_t ws_size,
                              hipStream_t stream)
{
    const int*   tokens = (const int*)d_in[0];
    const float* emb    = (const float*)d_in[1];
    const float* Wf     = (const float*)d_in[2];
    const float* Uf     = (const float*)d_in[3];
    const float* bfv    = (const float*)d_in[4];
    const float* Wb     = (const float*)d_in[5];
    const float* Ub     = (const float*)d_in[6];
    const float* bbv    = (const float*)d_in[7];
    const float* Wd     = (const float*)d_in[8];
    const float* bd     = (const float*)d_in[9];
    const float* trans  = (const float*)d_in[10];

    float* out     = (float*)d_out;
    float* dec_out = out;                                        // B*T
    float* pot_out = out + (size_t)BB * TT;                      // B*T*K
    float* seq_out = out + (size_t)BB * TT + (size_t)BB * TT * KK; // B

    float* potf = (float*)d_ws;
    float* potb = potf + (size_t)BB * TT * KK;
    unsigned short* embw = (unsigned short*)(potb + (size_t)BB * TT * KK);

    hipLaunchKernelGGL(embw_kernel, dim3((VP1 + 7) / 8), dim3(512), 0, stream,
                       emb, Wf, bfv, Wb, bbv, embw);
    hipLaunchKernelGGL(rec_kernel, dim3(64), dim3(256), 0, stream,
                       tokens, embw, Uf, Ub, Wd, potf, potb);
    hipLaunchKernelGGL(viterbi_kernel, dim3(BB), dim3(64), 0, stream,
                       tokens, potf, potb, bd, trans, dec_out, pot_out, seq_out);
}

// Round 3
// 746.384 us; speedup vs baseline: 2.1842x; 2.1842x over previous
//
#include <hip/hip_runtime.h>

#define BB 512
#define TT 512
#define EE 64
#define HH 64
#define KK 9
#define VP1 30001   // V+1 rows in emb

typedef __attribute__((ext_vector_type(8))) short short8;
typedef __attribute__((ext_vector_type(4))) float float4v;

__device__ __forceinline__ float sigm(float x) { return 1.0f / (1.0f + __expf(-x)); }
__device__ __forceinline__ float tanh_(float x) { return 1.0f - 2.0f / (__expf(2.0f * x) + 1.0f); }

__device__ __forceinline__ unsigned short f2bf(float f) {
    unsigned int u = __float_as_uint(f);
    unsigned int r = u + 0x7fffu + ((u >> 16) & 1u);
    return (unsigned short)(r >> 16);
}
__device__ __forceinline__ float bflo2f(unsigned int d) { return __uint_as_float(d << 16); }
__device__ __forceinline__ float bfhi2f(unsigned int d) { return __uint_as_float(d & 0xffff0000u); }

// barrier that does NOT drain vmcnt (keeps global prefetch loads in flight).
// 0xC07F = vmcnt(63) expcnt(7) lgkmcnt(0): wait LDS ops only.
__device__ __forceinline__ void block_sync_lds() {
    __builtin_amdgcn_s_waitcnt(0xC07F);
    __builtin_amdgcn_s_barrier();
}

// ---------------------------------------------------------------------------
// embW = [emb | bias-augmented] @ Wswizzled, bf16 out. MFMA GEMM.
// out col c = dir*256 + u*4 + g  maps to  W_dir[:, g*64+u], + bias baked into C.
// Block: 256 thr (4 waves), M-tile 64 vocab rows, wave w owns cols [128w,128w+128).
// ---------------------------------------------------------------------------
__global__ __launch_bounds__(256, 1)
void embw_kernel(const float* __restrict__ emb,
                 const float* __restrict__ Wf, const float* __restrict__ bfv,
                 const float* __restrict__ Wb, const float* __restrict__ bbv,
                 unsigned short* __restrict__ embw)
{
    const int v0 = blockIdx.x * 64;
    const int tid = threadIdx.x;
    const int w = tid >> 6, lane = tid & 63;
    const int l16 = lane & 15, quad = lane >> 4;

    // B fragments + per-col bias
    short8 bFr[8][2];
    float biasn[8];
#pragma unroll
    for (int n = 0; n < 8; ++n) {
        int c = w * 128 + n * 16 + l16;
        int dir = c >> 8, rem = c & 255;
        int u = rem >> 2, g = rem & 3;
        const float* Wp = dir ? Wb : Wf;
        int scol = g * 64 + u;
        biasn[n] = (dir ? bbv : bfv)[scol];
#pragma unroll
        for (int q = 0; q < 2; ++q) {
            short8 v;
#pragma unroll
            for (int j = 0; j < 8; ++j)
                v[j] = (short)f2bf(Wp[(q * 32 + quad * 8 + j) * 256 + scol]);
            bFr[n][q] = v;
        }
    }

    // A fragments (emb rows, f32 -> bf16), clamp OOB rows (stores guarded)
    short8 aFr[4][2];
#pragma unroll
    for (int mt = 0; mt < 4; ++mt) {
        int vrow = v0 + mt * 16 + l16;
        if (vrow >= VP1) vrow = VP1 - 1;
        const float* er = emb + (size_t)vrow * 64;
#pragma unroll
        for (int q = 0; q < 2; ++q) {
            const float* p = er + q * 32 + quad * 8;
            float4 x0 = *(const float4*)(p);
            float4 x1 = *(const float4*)(p + 4);
            short8 v;
            v[0] = (short)f2bf(x0.x); v[1] = (short)f2bf(x0.y);
            v[2] = (short)f2bf(x0.z); v[3] = (short)f2bf(x0.w);
            v[4] = (short)f2bf(x1.x); v[5] = (short)f2bf(x1.y);
            v[6] = (short)f2bf(x1.z); v[7] = (short)f2bf(x1.w);
            aFr[mt][q] = v;
        }
    }

    float4v acc[4][8];
#pragma unroll
    for (int mt = 0; mt < 4; ++mt)
#pragma unroll
        for (int n = 0; n < 8; ++n) {
            acc[mt][n][0] = biasn[n]; acc[mt][n][1] = biasn[n];
            acc[mt][n][2] = biasn[n]; acc[mt][n][3] = biasn[n];
        }
#pragma unroll
    for (int mt = 0; mt < 4; ++mt)
#pragma unroll
        for (int n = 0; n < 8; ++n) {
            acc[mt][n] = __builtin_amdgcn_mfma_f32_16x16x32_bf16(aFr[mt][0], bFr[n][0], acc[mt][n], 0, 0, 0);
            acc[mt][n] = __builtin_amdgcn_mfma_f32_16x16x32_bf16(aFr[mt][1], bFr[n][1], acc[mt][n], 0, 0, 0);
        }

#pragma unroll
    for (int mt = 0; mt < 4; ++mt)
#pragma unroll
        for (int n = 0; n < 8; ++n) {
            int cc = w * 128 + n * 16 + l16;
#pragma unroll
            for (int r = 0; r < 4; ++r) {
                int vrow = v0 + mt * 16 + quad * 4 + r;
                if (vrow < VP1)
                    embw[(size_t)vrow * 512 + cc] = f2bf(acc[mt][n][r]);
            }
        }
}

// ---------------------------------------------------------------------------
// Recurrence: grid 64 = 2 dirs x 32 row-slices (16 rows), 4 waves/block.
// Tokens staged in LDS; zx prefetched 4 steps deep (survives raw s_barrier);
// token rings 8 deep (LDS reads issued 8 steps early).
// ---------------------------------------------------------------------------
__global__ __launch_bounds__(256, 1)
void rec_kernel(const int* __restrict__ tokens,
                const unsigned short* __restrict__ embw,
                const float* __restrict__ Uf, const float* __restrict__ Ub,
                const float* __restrict__ Wd,
                float* __restrict__ potf, float* __restrict__ potb)
{
    const int blk = blockIdx.x;
    const int dir = blk >> 5;
    const int row0 = (blk & 31) * 16;
    const int tid = threadIdx.x;
    const int lane = tid & 63;
    const int w = tid >> 6;
    const int l16 = lane & 15, quad = lane >> 4;
    const int u = w * 16 + l16;

    const float* Up = dir ? Ub : Uf;
    float* pot = dir ? potb : potf;
    const uint2* embw2 = (const uint2*)embw;

    __shared__ int tokl[16][TT];                       // 32 KB
    __shared__ __align__(16) unsigned short hl[2][16][72];

    // stage this slice's tokens (coalesced)
    for (int i = tid; i < 16 * TT; i += 256) {
        int r = i >> 9, t = i & 511;
        tokl[r][t] = tokens[(row0 + r) * TT + t];
    }

    // U B-fragments
    short8 bU[4][2];
#pragma unroll
    for (int g = 0; g < 4; ++g)
#pragma unroll
        for (int q = 0; q < 2; ++q) {
            short8 v;
#pragma unroll
            for (int j = 0; j < 8; ++j) {
                int k = q * 32 + quad * 8 + j;
                v[j] = (short)f2bf(Up[k * 256 + g * 64 + u]);
            }
            bU[g][q] = v;
        }
    // Wd B-fragments
    short8 bW[2];
#pragma unroll
    for (int q = 0; q < 2; ++q) {
        short8 v;
#pragma unroll
        for (int j = 0; j < 8; ++j) {
            int k = q * 32 + quad * 8 + j;
            v[j] = (l16 < KK) ? (short)f2bf(Wd[(dir * 64 + k) * KK + l16]) : (short)0;
        }
        bW[q] = v;
    }

    __syncthreads();  // tokens staged (full drain OK, one-time)

    const int rloc = quad * 4;  // local row base for this lane

    // rings: tokA[d] = tok[step s+d'], tokB[d] = tok[step s+4+d'], zxp[d] = zx[step]
    int tokA[4][4], tokB[4][4];
    uint2 zxp[4][4];
#pragma unroll
    for (int d = 0; d < 4; ++d) {
        int td = dir ? (TT - 1 - d) : d;
        int td4 = dir ? (TT - 1 - (d + 4)) : (d + 4);
#pragma unroll
        for (int r = 0; r < 4; ++r) {
            tokA[d][r] = tokl[rloc + r][td];
            tokB[d][r] = tokl[rloc + r][td4];
        }
    }
#pragma unroll
    for (int d = 0; d < 4; ++d)
#pragma unroll
        for (int r = 0; r < 4; ++r)
            zxp[d][r] = embw2[(size_t)(tokA[d][r] * 2 + dir) * 64 + u];

    float c_st[4] = {0.f, 0.f, 0.f, 0.f};
    float h_st[4] = {0.f, 0.f, 0.f, 0.f};

    for (int sb = 0; sb < TT; sb += 4) {
#pragma unroll
        for (int ss = 0; ss < 4; ++ss) {
            const int s = sb + ss;
            // snapshot current step's tok/zx before ring refill
            int tcur[4]; uint2 zcur[4];
#pragma unroll
            for (int r = 0; r < 4; ++r) { tcur[r] = tokA[ss][r]; zcur[r] = zxp[ss][r]; }

            // publish h (state entering step s)
#pragma unroll
            for (int r = 0; r < 4; ++r)
                hl[s & 1][rloc + r][u] = f2bf(h_st[r]);

            // issue zx prefetch for step s+4 (stays in flight across raw barrier)
            if (s + 4 < TT) {
#pragma unroll
                for (int r = 0; r < 4; ++r)
                    zxp[ss][r] = embw2[(size_t)(tokB[ss][r] * 2 + dir) * 64 + u];
            }
#pragma unroll
            for (int r = 0; r < 4; ++r) tokA[ss][r] = tokB[ss][r];

            block_sync_lds();

            // A-fragments of h
            const unsigned short* hrow = &hl[s & 1][l16][0];
            short8 a0 = *(const short8*)(hrow + quad * 8);
            short8 a1 = *(const short8*)(hrow + 32 + quad * 8);

            // token ring refill for step s+8 (LDS; drained at NEXT barrier)
            if (s + 8 < TT) {
                int t8 = dir ? (TT - 1 - (s + 8)) : (s + 8);
#pragma unroll
                for (int r = 0; r < 4; ++r) tokB[ss][r] = tokl[rloc + r][t8];
            }

            // z = zx + h @ U
            float4v accg[4];
#pragma unroll
            for (int r = 0; r < 4; ++r) {
                accg[0][r] = bflo2f(zcur[r].x);
                accg[1][r] = bfhi2f(zcur[r].x);
                accg[2][r] = bflo2f(zcur[r].y);
                accg[3][r] = bfhi2f(zcur[r].y);
            }
#pragma unroll
            for (int g = 0; g < 4; ++g) {
                accg[g] = __builtin_amdgcn_mfma_f32_16x16x32_bf16(a0, bU[g][0], accg[g], 0, 0, 0);
                accg[g] = __builtin_amdgcn_mfma_f32_16x16x32_bf16(a1, bU[g][1], accg[g], 0, 0, 0);
            }

            // potentials for previous step, rotated across waves
            if (s > 0 && w == (s & 3)) {
                float4v accP = {0.f, 0.f, 0.f, 0.f};
                accP = __builtin_amdgcn_mfma_f32_16x16x32_bf16(a0, bW[0], accP, 0, 0, 0);
                accP = __builtin_amdgcn_mfma_f32_16x16x32_bf16(a1, bW[1], accP, 0, 0, 0);
                int tprev = dir ? (TT - s) : (s - 1);
                if (l16 < KK) {
#pragma unroll
                    for (int r = 0; r < 4; ++r)
                        pot[((size_t)(row0 + rloc + r) * TT + tprev) * KK + l16] = accP[r];
                }
            }

            // gates
#pragma unroll
            for (int r = 0; r < 4; ++r) {
                float zi = accg[0][r], zf = accg[1][r], zg = accg[2][r], zo = accg[3][r];
                float cn = sigm(zf) * c_st[r] + sigm(zi) * tanh_(zg);
                float hn = sigm(zo) * tanh_(cn);
                bool m = (tcur[r] != 0);
                h_st[r] = m ? hn : h_st[r];
                c_st[r] = m ? cn : c_st[r];
            }
        }
    }

    // epilogue: potential for the final step (hl buffer parity: TT&1 == 0)
#pragma unroll
    for (int r = 0; r < 4; ++r)
        hl[0][rloc + r][u] = f2bf(h_st[r]);
    block_sync_lds();
    if (w == 0) {
        const unsigned short* hrow = &hl[0][l16][0];
        short8 a0 = *(const short8*)(hrow + quad * 8);
        short8 a1 = *(const short8*)(hrow + 32 + quad * 8);
        float4v accP = {0.f, 0.f, 0.f, 0.f};
        accP = __builtin_amdgcn_mfma_f32_16x16x32_bf16(a0, bW[0], accP, 0, 0, 0);
        accP = __builtin_amdgcn_mfma_f32_16x16x32_bf16(a1, bW[1], accP, 0, 0, 0);
        int tlast = dir ? 0 : (TT - 1);
        if (l16 < KK) {
#pragma unroll
            for (int r = 0; r < 4; ++r)
                pot[((size_t)(row0 + rloc + r) * TT + tlast) * KK + l16] = accP[r];
        }
    }
}

// ---------------------------------------------------------------------------
// Fused combine + Viterbi. One wave per batch row; hoisted shuffles +
// tree argmax (first-max tie rule); segmented parallel backtrace.
// ---------------------------------------------------------------------------
__global__ __launch_bounds__(64)
void viterbi_kernel(const int* __restrict__ tokens,
                    const float* __restrict__ potf, const float* __restrict__ potb,
                    const float* __restrict__ bd, const float* __restrict__ trans,
                    float* __restrict__ dec_out, float* __restrict__ pot_out,
                    float* __restrict__ seq_out)
{
    const int row = blockIdx.x;
    const int lane = threadIdx.x;

    __shared__ float pl[TT * KK];
    __shared__ unsigned char bpl[(TT - 1) * KK];
    __shared__ unsigned char maskl[TT];
    __shared__ unsigned char segmap[64][KK];
    __shared__ unsigned char bseq[65];
    __shared__ float decl_[TT];

    int cnt = 0;
#pragma unroll
    for (int ch = 0; ch < TT / 64; ++ch) {
        int tk = tokens[row * TT + ch * 64 + lane];
        int m = (tk != 0) ? 1 : 0;
        maskl[ch * 64 + lane] = (unsigned char)m;
        cnt += m;
    }
    for (int off = 32; off > 0; off >>= 1) cnt += __shfl_down(cnt, off);
    if (lane == 0) seq_out[row] = (float)cnt;

    const size_t base = (size_t)row * (TT * KK);
    for (int i = 0; i < (TT * KK) / 64; ++i) {
        int li = i * 64 + lane;
        float s = potf[base + li] + potb[base + li];
        pl[li] = s;
        pot_out[base + li] = s + bd[li % KK];
    }
    __syncthreads();

    float bdv = (lane < KK) ? bd[lane] : 0.f;
    float treg[KK];
#pragma unroll
    for (int i = 0; i < KK; ++i) treg[i] = (lane < KK) ? trans[i * KK + lane] : 0.f;

    float alpha = (lane < KK) ? (pl[lane] + bdv) : -1e30f;
    for (int t = 1; t < TT; ++t) {
        float p = (lane < KK) ? (pl[t * KK + lane] + bdv) : 0.f;
        float sc[KK];
#pragma unroll
        for (int i = 0; i < KK; ++i) sc[i] = __shfl(alpha, i) + treg[i];
        // tree argmax, first-max tie rule (strict > with higher-index challenger)
        float b0 = sc[0]; int i0 = 0;
        if (sc[1] > b0) { b0 = sc[1]; i0 = 1; }
        float b1 = sc[2]; int i1 = 2;
        if (sc[3] > b1) { b1 = sc[3]; i1 = 3; }
        float b2 = sc[4]; int i2 = 4;
        if (sc[5] > b2) { b2 = sc[5]; i2 = 5; }
        float b3 = sc[6]; int i3 = 6;
        if (sc[7] > b3) { b3 = sc[7]; i3 = 7; }
        if (b1 > b0) { b0 = b1; i0 = i1; }
        if (b3 > b2) { b2 = b3; i2 = i3; }
        if (b2 > b0) { b0 = b2; i0 = i2; }
        if (sc[8] > b0) { b0 = sc[8]; i0 = 8; }

        bool m = maskl[t] != 0;
        alpha = m ? (b0 + p) : alpha;
        int bpv = m ? i0 : lane;
        if (lane < KK) bpl[(t - 1) * KK + lane] = (unsigned char)bpv;
    }
    // final argmax of alpha
    float sc[KK];
#pragma unroll
    for (int i = 0; i < KK; ++i) sc[i] = __shfl(alpha, i);
    float b0 = sc[0]; int last = 0;
#pragma unroll
    for (int i = 1; i < KK; ++i)
        if (sc[i] > b0) { b0 = sc[i]; last = i; }
    __syncthreads();

    // segmented backtrace
    {
        int l = lane;
#pragma unroll
        for (int x = 0; x < KK; ++x) {
            int y = x;
#pragma unroll
            for (int d = 7; d >= 0; --d) {
                int t = 8 * l + d;
                if (t < TT - 1) y = bpl[t * KK + y];
            }
            segmap[l][x] = (unsigned char)y;
        }
    }
    __syncthreads();
    if (lane == 0) {
        int cur = last;
        bseq[64] = (unsigned char)last;
        for (int l = 63; l >= 0; --l) {
            cur = segmap[l][cur];
            bseq[l] = (unsigned char)cur;
        }
    }
    __syncthreads();
    {
        int l = lane;
        int cur = bseq[l + 1];
#pragma unroll
        for (int d = 7; d >= 0; --d) {
            int t = 8 * l + d;
            if (t < TT - 1) cur = bpl[t * KK + cur];
            decl_[t] = (maskl[t] != 0) ? (float)cur : 0.f;
        }
    }
    __syncthreads();
#pragma unroll
    for (int ch = 0; ch < TT / 64; ++ch)
        dec_out[(size_t)row * TT + ch * 64 + lane] = decl_[ch * 64 + lane];
}

extern "C" void kernel_launch(void* const* d_in, const int* in_sizes, int n_in,
                              void* d_out, int out_size, void* d_ws, size_t ws_size,
                              hipStream_t stream)
{
    const int*   tokens = (const int*)d_in[0];
    const float* emb    = (const float*)d_in[1];
    const float* Wf     = (const float*)d_in[2];
    const float* Uf     = (const float*)d_in[3];
    const float* bfv    = (const float*)d_in[4];
    const float* Wb     = (const float*)d_in[5];
    const float* Ub     = (const float*)d_in[6];
    const float* bbv    = (const float*)d_in[7];
    const float* Wd     = (const float*)d_in[8];
    const float* bd     = (const float*)d_in[9];
    const float* trans  = (const float*)d_in[10];

    float* out     = (float*)d_out;
    float* dec_out = out;                                          // B*T
    float* pot_out = out + (size_t)BB * TT;                        // B*T*K
    float* seq_out = out + (size_t)BB * TT + (size_t)BB * TT * KK; // B

    float* potf = (float*)d_ws;
    float* potb = potf + (size_t)BB * TT * KK;
    unsigned short* embw = (unsigned short*)(potb + (size_t)BB * TT * KK);

    hipLaunchKernelGGL(embw_kernel, dim3(469), dim3(256), 0, stream,
                       emb, Wf, bfv, Wb, bbv, embw);
    hipLaunchKernelGGL(rec_kernel, dim3(64), dim3(256), 0, stream,
                       tokens, embw, Uf, Ub, Wd, potf, potb);
    hipLaunchKernelGGL(viterbi_kernel, dim3(BB), dim3(64), 0, stream,
                       tokens, potf, potb, bd, trans, dec_out, pot_out, seq_out);
}

// Round 4
// 471.482 us; speedup vs baseline: 3.4577x; 1.5831x over previous
//
#include <hip/hip_runtime.h>

#define BB 512
#define TT 512
#define EE 64
#define HH 64
#define KK 9
#define VP1 30001   // V+1 rows in emb

typedef __attribute__((ext_vector_type(8))) short short8;
typedef __attribute__((ext_vector_type(4))) float float4v;

__device__ __forceinline__ float sigm(float x) { return 1.0f / (1.0f + __expf(-x)); }
__device__ __forceinline__ float tanh_(float x) { return 1.0f - 2.0f / (__expf(2.0f * x) + 1.0f); }

__device__ __forceinline__ unsigned short f2bf(float f) {
    unsigned int u = __float_as_uint(f);
    unsigned int r = u + 0x7fffu + ((u >> 16) & 1u);
    return (unsigned short)(r >> 16);
}
__device__ __forceinline__ float bflo2f(unsigned int d) { return __uint_as_float(d << 16); }
__device__ __forceinline__ float bfhi2f(unsigned int d) { return __uint_as_float(d & 0xffff0000u); }

// barrier that does NOT drain vmcnt (keeps global prefetch loads in flight).
// 0xC07F = vmcnt(63) expcnt(7) lgkmcnt(0): wait LDS ops only.
__device__ __forceinline__ void block_sync_lds() {
    __builtin_amdgcn_s_waitcnt(0xC07F);
    __builtin_amdgcn_s_barrier();
}

// ---------------------------------------------------------------------------
// embW = emb @ Wswizzled + bias, bf16 out. MFMA GEMM.
// out col c = dir*256 + u*4 + g  maps to  W_dir[:, g*64+u].
// ---------------------------------------------------------------------------
__global__ __launch_bounds__(256, 1)
void embw_kernel(const float* __restrict__ emb,
                 const float* __restrict__ Wf, const float* __restrict__ bfv,
                 const float* __restrict__ Wb, const float* __restrict__ bbv,
                 unsigned short* __restrict__ embw)
{
    const int v0 = blockIdx.x * 64;
    const int tid = threadIdx.x;
    const int w = tid >> 6, lane = tid & 63;
    const int l16 = lane & 15, quad = lane >> 4;

    short8 bFr[8][2];
    float biasn[8];
#pragma unroll
    for (int n = 0; n < 8; ++n) {
        int c = w * 128 + n * 16 + l16;
        int dir = c >> 8, rem = c & 255;
        int u = rem >> 2, g = rem & 3;
        const float* Wp = dir ? Wb : Wf;
        int scol = g * 64 + u;
        biasn[n] = (dir ? bbv : bfv)[scol];
#pragma unroll
        for (int q = 0; q < 2; ++q) {
            short8 v;
#pragma unroll
            for (int j = 0; j < 8; ++j)
                v[j] = (short)f2bf(Wp[(q * 32 + quad * 8 + j) * 256 + scol]);
            bFr[n][q] = v;
        }
    }

    short8 aFr[4][2];
#pragma unroll
    for (int mt = 0; mt < 4; ++mt) {
        int vrow = v0 + mt * 16 + l16;
        if (vrow >= VP1) vrow = VP1 - 1;
        const float* er = emb + (size_t)vrow * 64;
#pragma unroll
        for (int q = 0; q < 2; ++q) {
            const float* p = er + q * 32 + quad * 8;
            float4 x0 = *(const float4*)(p);
            float4 x1 = *(const float4*)(p + 4);
            short8 v;
            v[0] = (short)f2bf(x0.x); v[1] = (short)f2bf(x0.y);
            v[2] = (short)f2bf(x0.z); v[3] = (short)f2bf(x0.w);
            v[4] = (short)f2bf(x1.x); v[5] = (short)f2bf(x1.y);
            v[6] = (short)f2bf(x1.z); v[7] = (short)f2bf(x1.w);
            aFr[mt][q] = v;
        }
    }

    float4v acc[4][8];
#pragma unroll
    for (int mt = 0; mt < 4; ++mt)
#pragma unroll
        for (int n = 0; n < 8; ++n) {
            acc[mt][n][0] = biasn[n]; acc[mt][n][1] = biasn[n];
            acc[mt][n][2] = biasn[n]; acc[mt][n][3] = biasn[n];
        }
#pragma unroll
    for (int mt = 0; mt < 4; ++mt)
#pragma unroll
        for (int n = 0; n < 8; ++n) {
            acc[mt][n] = __builtin_amdgcn_mfma_f32_16x16x32_bf16(aFr[mt][0], bFr[n][0], acc[mt][n], 0, 0, 0);
            acc[mt][n] = __builtin_amdgcn_mfma_f32_16x16x32_bf16(aFr[mt][1], bFr[n][1], acc[mt][n], 0, 0, 0);
        }

#pragma unroll
    for (int mt = 0; mt < 4; ++mt)
#pragma unroll
        for (int n = 0; n < 8; ++n) {
            int cc = w * 128 + n * 16 + l16;
#pragma unroll
            for (int r = 0; r < 4; ++r) {
                int vrow = v0 + mt * 16 + quad * 4 + r;
                if (vrow < VP1)
                    embw[(size_t)vrow * 512 + cc] = f2bf(acc[mt][n][r]);
            }
        }
}

// ---------------------------------------------------------------------------
// Recurrence: grid 256 = 2 dirs x 128 slices of 4 rows -> full chip.
// 4 real rows mapped to MFMA C rows {0,4,8,12} (reg=0), so gates / zx unpack /
// publish / gather are ONE element per lane. Garbage h rows stay zero in LDS.
// Lane (w,quad,l16): row_local = quad, unit u = w*16+l16.
// ---------------------------------------------------------------------------
__global__ __launch_bounds__(256, 1)
void rec_kernel(const int* __restrict__ tokens,
                const unsigned short* __restrict__ embw,
                const float* __restrict__ Uf, const float* __restrict__ Ub,
                const float* __restrict__ Wd,
                float* __restrict__ potf, float* __restrict__ potb)
{
    const int blk = blockIdx.x;
    const int dir = blk >> 7;
    const int row0 = (blk & 127) * 4;
    const int tid = threadIdx.x;
    const int lane = tid & 63;
    const int w = tid >> 6;
    const int l16 = lane & 15, quad = lane >> 4;
    const int u = w * 16 + l16;

    const float* Up = dir ? Ub : Uf;
    float* pot = dir ? potb : potf;
    const uint2* embw2 = (const uint2*)embw;

    __shared__ int tokl[4][TT];                        // 8 KB
    __shared__ __align__(16) unsigned short hl[2][16][72];

    // zero-init hl (garbage rows must stay 0), stage tokens
    for (int i = tid; i < 2 * 16 * 72; i += 256)
        ((unsigned short*)hl)[i] = 0;
    for (int i = tid; i < 4 * TT; i += 256) {
        int r = i >> 9, t = i & 511;
        tokl[r][t] = tokens[(row0 + r) * TT + t];
    }

    // U B-fragments: bU[g][q][j] = U[k=q*32+quad*8+j][g*64+u]
    short8 bU[4][2];
#pragma unroll
    for (int g = 0; g < 4; ++g)
#pragma unroll
        for (int q = 0; q < 2; ++q) {
            short8 v;
#pragma unroll
            for (int j = 0; j < 8; ++j) {
                int k = q * 32 + quad * 8 + j;
                v[j] = (short)f2bf(Up[k * 256 + g * 64 + u]);
            }
            bU[g][q] = v;
        }
    // Wd B-fragments
    short8 bW[2];
#pragma unroll
    for (int q = 0; q < 2; ++q) {
        short8 v;
#pragma unroll
        for (int j = 0; j < 8; ++j) {
            int k = q * 32 + quad * 8 + j;
            v[j] = (l16 < KK) ? (short)f2bf(Wd[(dir * 64 + k) * KK + l16]) : (short)0;
        }
        bW[q] = v;
    }

    __syncthreads();  // hl zeroed + tokens staged (one-time full drain)

    // per-lane rings (row_local = quad): tokA = steps s..s+3, tokB = s+4..s+7
    int tokA[4], tokB[4];
    uint2 zxp[4];
#pragma unroll
    for (int d = 0; d < 4; ++d) {
        int td = dir ? (TT - 1 - d) : d;
        int td4 = dir ? (TT - 1 - (d + 4)) : (d + 4);
        tokA[d] = tokl[quad][td];
        tokB[d] = tokl[quad][td4];
    }
#pragma unroll
    for (int d = 0; d < 4; ++d)
        zxp[d] = embw2[(size_t)(tokA[d] * 2 + dir) * 64 + u];

    float c_st = 0.f, h_st = 0.f;

    for (int sb = 0; sb < TT; sb += 4) {
#pragma unroll
        for (int ss = 0; ss < 4; ++ss) {
            const int s = sb + ss;
            int tcur = tokA[ss];
            uint2 zcur = zxp[ss];

            // publish h (state entering step s) -> row m = quad*4
            hl[s & 1][quad * 4][u] = f2bf(h_st);

            // zx prefetch for step s+4 (survives raw barrier)
            if (s + 4 < TT)
                zxp[ss] = embw2[(size_t)(tokB[ss] * 2 + dir) * 64 + u];
            tokA[ss] = tokB[ss];

            block_sync_lds();

            const unsigned short* hrow = &hl[s & 1][l16][0];
            short8 a0 = *(const short8*)(hrow + quad * 8);
            short8 a1 = *(const short8*)(hrow + 32 + quad * 8);

            // token ring refill for step s+8 (LDS, drained at next barrier)
            if (s + 8 < TT) {
                int t8 = dir ? (TT - 1 - (s + 8)) : (s + 8);
                tokB[ss] = tokl[quad][t8];
            }

            // z = zx + h @ U  (only elem 0 = row quad*4 is real)
            float4v accg[4];
#pragma unroll
            for (int g = 0; g < 4; ++g) { accg[g][1] = 0.f; accg[g][2] = 0.f; accg[g][3] = 0.f; }
            accg[0][0] = bflo2f(zcur.x);
            accg[1][0] = bfhi2f(zcur.x);
            accg[2][0] = bflo2f(zcur.y);
            accg[3][0] = bfhi2f(zcur.y);
#pragma unroll
            for (int g = 0; g < 4; ++g) {
                accg[g] = __builtin_amdgcn_mfma_f32_16x16x32_bf16(a0, bU[g][0], accg[g], 0, 0, 0);
                accg[g] = __builtin_amdgcn_mfma_f32_16x16x32_bf16(a1, bU[g][1], accg[g], 0, 0, 0);
            }

            // potentials for previous step, rotated across waves (elem 0 only)
            if (s > 0 && w == (s & 3)) {
                float4v accP = {0.f, 0.f, 0.f, 0.f};
                accP = __builtin_amdgcn_mfma_f32_16x16x32_bf16(a0, bW[0], accP, 0, 0, 0);
                accP = __builtin_amdgcn_mfma_f32_16x16x32_bf16(a1, bW[1], accP, 0, 0, 0);
                int tprev = dir ? (TT - s) : (s - 1);
                if (l16 < KK)
                    pot[((size_t)(row0 + quad) * TT + tprev) * KK + l16] = accP[0];
            }

            // gates: ONE element per lane
            {
                float zi = accg[0][0], zf = accg[1][0], zg = accg[2][0], zo = accg[3][0];
                float cn = sigm(zf) * c_st + sigm(zi) * tanh_(zg);
                float hn = sigm(zo) * tanh_(cn);
                bool m = (tcur != 0);
                h_st = m ? hn : h_st;
                c_st = m ? cn : c_st;
            }
        }
    }

    // epilogue: final step's potential
    hl[0][quad * 4][u] = f2bf(h_st);
    block_sync_lds();
    if (w == 0) {
        const unsigned short* hrow = &hl[0][l16][0];
        short8 a0 = *(const short8*)(hrow + quad * 8);
        short8 a1 = *(const short8*)(hrow + 32 + quad * 8);
        float4v accP = {0.f, 0.f, 0.f, 0.f};
        accP = __builtin_amdgcn_mfma_f32_16x16x32_bf16(a0, bW[0], accP, 0, 0, 0);
        accP = __builtin_amdgcn_mfma_f32_16x16x32_bf16(a1, bW[1], accP, 0, 0, 0);
        int tlast = dir ? 0 : (TT - 1);
        if (l16 < KK)
            pot[((size_t)(row0 + quad) * TT + tlast) * KK + l16] = accP[0];
    }
}

// ---------------------------------------------------------------------------
// Fused combine + Viterbi (one wave per row; tree argmax; parallel backtrace)
// ---------------------------------------------------------------------------
__global__ __launch_bounds__(64)
void viterbi_kernel(const int* __restrict__ tokens,
                    const float* __restrict__ potf, const float* __restrict__ potb,
                    const float* __restrict__ bd, const float* __restrict__ trans,
                    float* __restrict__ dec_out, float* __restrict__ pot_out,
                    float* __restrict__ seq_out)
{
    const int row = blockIdx.x;
    const int lane = threadIdx.x;

    __shared__ float pl[TT * KK];
    __shared__ unsigned char bpl[(TT - 1) * KK];
    __shared__ unsigned char maskl[TT];
    __shared__ unsigned char segmap[64][KK];
    __shared__ unsigned char bseq[65];
    __shared__ float decl_[TT];

    int cnt = 0;
#pragma unroll
    for (int ch = 0; ch < TT / 64; ++ch) {
        int tk = tokens[row * TT + ch * 64 + lane];
        int m = (tk != 0) ? 1 : 0;
        maskl[ch * 64 + lane] = (unsigned char)m;
        cnt += m;
    }
    for (int off = 32; off > 0; off >>= 1) cnt += __shfl_down(cnt, off);
    if (lane == 0) seq_out[row] = (float)cnt;

    const size_t base = (size_t)row * (TT * KK);
    for (int i = 0; i < (TT * KK) / 64; ++i) {
        int li = i * 64 + lane;
        float s = potf[base + li] + potb[base + li];
        pl[li] = s;
        pot_out[base + li] = s + bd[li % KK];
    }
    __syncthreads();

    float bdv = (lane < KK) ? bd[lane] : 0.f;
    float treg[KK];
#pragma unroll
    for (int i = 0; i < KK; ++i) treg[i] = (lane < KK) ? trans[i * KK + lane] : 0.f;

    float alpha = (lane < KK) ? (pl[lane] + bdv) : -1e30f;
    for (int t = 1; t < TT; ++t) {
        float p = (lane < KK) ? (pl[t * KK + lane] + bdv) : 0.f;
        float sc[KK];
#pragma unroll
        for (int i = 0; i < KK; ++i) sc[i] = __shfl(alpha, i) + treg[i];
        float b0 = sc[0]; int i0 = 0;
        if (sc[1] > b0) { b0 = sc[1]; i0 = 1; }
        float b1 = sc[2]; int i1 = 2;
        if (sc[3] > b1) { b1 = sc[3]; i1 = 3; }
        float b2 = sc[4]; int i2 = 4;
        if (sc[5] > b2) { b2 = sc[5]; i2 = 5; }
        float b3 = sc[6]; int i3 = 6;
        if (sc[7] > b3) { b3 = sc[7]; i3 = 7; }
        if (b1 > b0) { b0 = b1; i0 = i1; }
        if (b3 > b2) { b2 = b3; i2 = i3; }
        if (b2 > b0) { b0 = b2; i0 = i2; }
        if (sc[8] > b0) { b0 = sc[8]; i0 = 8; }

        bool m = maskl[t] != 0;
        alpha = m ? (b0 + p) : alpha;
        int bpv = m ? i0 : lane;
        if (lane < KK) bpl[(t - 1) * KK + lane] = (unsigned char)bpv;
    }
    float sc[KK];
#pragma unroll
    for (int i = 0; i < KK; ++i) sc[i] = __shfl(alpha, i);
    float b0 = sc[0]; int last = 0;
#pragma unroll
    for (int i = 1; i < KK; ++i)
        if (sc[i] > b0) { b0 = sc[i]; last = i; }
    __syncthreads();

    {
        int l = lane;
#pragma unroll
        for (int x = 0; x < KK; ++x) {
            int y = x;
#pragma unroll
            for (int d = 7; d >= 0; --d) {
                int t = 8 * l + d;
                if (t < TT - 1) y = bpl[t * KK + y];
            }
            segmap[l][x] = (unsigned char)y;
        }
    }
    __syncthreads();
    if (lane == 0) {
        int cur = last;
        bseq[64] = (unsigned char)last;
        for (int l = 63; l >= 0; --l) {
            cur = segmap[l][cur];
            bseq[l] = (unsigned char)cur;
        }
    }
    __syncthreads();
    {
        int l = lane;
        int cur = bseq[l + 1];
#pragma unroll
        for (int d = 7; d >= 0; --d) {
            int t = 8 * l + d;
            if (t < TT - 1) cur = bpl[t * KK + cur];
            decl_[t] = (maskl[t] != 0) ? (float)cur : 0.f;
        }
    }
    __syncthreads();
#pragma unroll
    for (int ch = 0; ch < TT / 64; ++ch)
        dec_out[(size_t)row * TT + ch * 64 + lane] = decl_[ch * 64 + lane];
}

extern "C" void kernel_launch(void* const* d_in, const int* in_sizes, int n_in,
                              void* d_out, int out_size, void* d_ws, size_t ws_size,
                              hipStream_t stream)
{
    const int*   tokens = (const int*)d_in[0];
    const float* emb    = (const float*)d_in[1];
    const float* Wf     = (const float*)d_in[2];
    const float* Uf     = (const float*)d_in[3];
    const float* bfv    = (const float*)d_in[4];
    const float* Wb     = (const float*)d_in[5];
    const float* Ub     = (const float*)d_in[6];
    const float* bbv    = (const float*)d_in[7];
    const float* Wd     = (const float*)d_in[8];
    const float* bd     = (const float*)d_in[9];
    const float* trans  = (const float*)d_in[10];

    float* out     = (float*)d_out;
    float* dec_out = out;
    float* pot_out = out + (size_t)BB * TT;
    float* seq_out = out + (size_t)BB * TT + (size_t)BB * TT * KK;

    float* potf = (float*)d_ws;
    float* potb = potf + (size_t)BB * TT * KK;
    unsigned short* embw = (unsigned short*)(potb + (size_t)BB * TT * KK);

    hipLaunchKernelGGL(embw_kernel, dim3(469), dim3(256), 0, stream,
                       emb, Wf, bfv, Wb, bbv, embw);
    hipLaunchKernelGGL(rec_kernel, dim3(256), dim3(256), 0, stream,
                       tokens, embw, Uf, Ub, Wd, potf, potb);
    hipLaunchKernelGGL(viterbi_kernel, dim3(BB), dim3(64), 0, stream,
                       tokens, potf, potb, bd, trans, dec_out, pot_out, seq_out);
}